// Round 2
// baseline (215.692 us; speedup 1.0000x reference)
//
#include <hip/hip_runtime.h>
#include <stdint.h>
#include <math.h>

#define T_STEPS 4096
#define BATCH   256
#define NB_BLK  256      // 16-step spike blocks per chain (scan2/3 bitmap granularity)
#define SEG     8        // cert segment length (time steps)
#define NSEG    512      // T/SEG cert segments per batch
#define NCHUNK  8        // chunks per batch (64 segments = 512 steps = 32 KiB each)

// LIF step, threshold=1:  v'=alpha*v+xs; s=max(floor(v'),0); v=v'-s
// Identity: v_new = min(v', fract(v')); s = v' - v_new (exact fp32).
// No-spike step (0<=v'<1 or v'<0) is EXACTLY v = fma(alpha, v, xs).
__device__ __forceinline__ float lif_step(float& v, float xs, float alpha) {
    float vp = fmaf(alpha, v, xs);
    float fr = vp - floorf(vp);
    float vn = fminf(vp, fr);
    float s  = vp - vn;
    v = vn;
    return s;
}

__device__ __forceinline__ float ubf(uint32_t w, int k) {
    return (float)((w >> (k * 8)) & 0xffu);
}

__device__ __forceinline__ float dot16(const float wr[16],
    float4 c0, float4 c1, float4 c2, float4 c3)
{
    float p0 = fmaf(wr[1], c0.y, wr[0] * c0.x);
    p0 = fmaf(wr[2], c0.z, p0);  p0 = fmaf(wr[3], c0.w, p0);
    float p1 = fmaf(wr[5], c1.y, wr[4] * c1.x);
    p1 = fmaf(wr[6], c1.z, p1);  p1 = fmaf(wr[7], c1.w, p1);
    float p2 = fmaf(wr[9], c2.y, wr[8] * c2.x);
    p2 = fmaf(wr[10], c2.z, p2); p2 = fmaf(wr[11], c2.w, p2);
    float p3 = fmaf(wr[13], c3.y, wr[12] * c3.x);
    p3 = fmaf(wr[14], c3.z, p3); p3 = fmaf(wr[15], c3.w, p3);
    return (p0 + p1) + (p2 + p3);
}

// Direct global->LDS DMA, 16 B per lane, no VGPR round-trip.
__device__ __forceinline__ void load_lds16(const float* g, float* l) {
    __builtin_amdgcn_global_load_lds(
        (const __attribute__((address_space(1))) void*)g,
        (__attribute__((address_space(3))) void*)l, 16, 0, 0);
}

// R15 structure:
//  * 8-step cert segments (512/batch), chunks of 64 segments = 32 KiB,
//    DOUBLE-BUFFERED in LDS (2 x 8192 floats) -> DMA of chunk k+1/k+2
//    overlaps compute of chunk k.  Counted waits: s_waitcnt vmcnt(2)
//    (never 0 in the loop) -- loads stay in flight across iterations.
//    Waits are asm volatile with "memory" clobber so the compiler cannot
//    move LDS reads / stores across them.  vmcnt retires IN ORDER, so ops
//    issued BEFORE the first chunk's loads (out-zero stores, weight loads)
//    are automatically covered by the first vmcnt(2).
//  * Wave-private staging as before: wave wv owns in-chunk segments
//    wv*4..wv*4+3 (2 KiB) = 2 global_load_lds instrs; its compute lanes
//    (sg = tid>>4) read exactly those segments -> NO __syncthreads in loop.
//  * LDS layout is linear (pitch 128 floats, required by global_load_lds);
//    the 4-way read bank conflict is fixed by XOR-swizzle: row j of in-wave
//    segment s2 sits at row-slot j^s2.  Swizzle applied on the GLOBAL source
//    address (linear LDS dest) and on the LDS read -- both sides, rule #21.
//  * Cert arrays: sh_end fp32 (needed exact-ish for composition/repair
//    jumps), m0/m1 quantized u8 with conservative round-UP (bound is
//    monotone increasing in m0,m1 -> false-bad only, never false-good).
//  * Composition parallelized 4x: 64 lanes = 16 ch x 4 quarter-chains,
//    20-segment warm-up per quarter (carry error <= 2*alpha8^20 = 6.7e-4
//    inside the 1e-3 guard band).
//  * scan2/scan3 FUSED as tail phases (all dataflow is per-batch);
//    bm1/bm2/flag2 live in LDS; 1 launch instead of 3.
__global__ __launch_bounds__(1024) void fused(
    const float* __restrict__ x, const float* __restrict__ w1,
    const float* __restrict__ w2, const float* __restrict__ w3,
    float* __restrict__ out, uint8_t* __restrict__ s1t,
    uint8_t* __restrict__ s2t,
    float alpha, float one_m, float alpha8)
{
    const int tid = threadIdx.x;
    const int b   = blockIdx.x;

    __shared__ __align__(16) float xbuf[2][8192];        // 64 KiB double buffer
    __shared__ float    sh_end[NSEG][16];                // 32 KiB (fp32)
    __shared__ uint8_t  sh_q0[NSEG][16];                 // 8 KiB (m0 quantized)
    __shared__ uint8_t  sh_q1[NSEG][16];                 // 8 KiB (m1 quantized)
    __shared__ uint32_t sh_badseg[16][NSEG / 32];        // 1 KiB bitmask
    __shared__ uint8_t  sh_bm1[NB_BLK];                  // 256 B
    __shared__ uint8_t  sh_bm2[NB_BLK];                  // 256 B
    __shared__ int      sh_badch, sh_spike, sh_flag2;

    const int co = tid & 15;
    const int sg = tid >> 4;          // 0..63 in-chunk segment
    const int wv = tid >> 6;          // wave 0..15
    const int ln = tid & 63;          // lane 0..63

    const float* xb = x + (size_t)b * T_STEPS * 16;      // 65536 floats

    // ---- LDS flag/bitmap init (before any barrier) ------------------------
    if (tid < 64)        ((uint32_t*)sh_bm1)[tid] = 0u;
    else if (tid < 128)  ((uint32_t*)sh_bm2)[tid - 64] = 0u;
    else if (tid == 128) { sh_badch = 0; sh_spike = 0; sh_flag2 = 0; }

    // ---- zero out[b] (stores retire before chunk0 loads -> covered by the
    //      first vmcnt(2); they drain into L2 during the DMA prologue) ------
    float4* o4 = (float4*)(out + (size_t)b * T_STEPS * 10);   // 10240 float4
    float4 z4 = make_float4(0.f, 0.f, 0.f, 0.f);
#pragma unroll
    for (int i = 0; i < 10; ++i) o4[i * 1024 + tid] = z4;

    float wr[16];
#pragma unroll
    for (int i = 0; i < 16; ++i) wr[i] = one_m * w1[co * 16 + i];

    // ---- per-lane DMA addressing (swizzled global source, linear LDS) -----
    const int s2a = (ln >> 5);            // in-wave segment of instr 0: 0..1
    const int s2b = s2a + 2;              // instr 1: 2..3
    const int jj  = (ln >> 2) & 7;        // LDS row-slot this lane fills
    const int qq  = ln & 3;               // 16B quad within row
    // source fetches global row (jj ^ s2) into LDS slot jj  (self-inverse)
    const int offA = wv * 512 + s2a * 128 + ((jj ^ s2a) << 4) + (qq << 2);
    const int offB = wv * 512 + s2b * 128 + ((jj ^ s2b) << 4) + (qq << 2);
    const int ldsA = wv * 512 + (ln << 2);
    const int ldsB = wv * 512 + 256 + (ln << 2);

    // prologue: chunk0 -> buf0, chunk1 -> buf1
    load_lds16(xb + offA, &xbuf[0][ldsA]);
    load_lds16(xb + offB, &xbuf[0][ldsB]);
    load_lds16(xb + 8192 + offA, &xbuf[1][ldsA]);
    load_lds16(xb + 8192 + offB, &xbuf[1][ldsB]);

    const int s23 = sg & 3;               // read-side swizzle key
    for (int k = 0; k < NCHUNK; ++k) {
        // wait for chunk k's 2 loads (k+1's stay in flight); everything
        // issued earlier (stores, weights) retires first (in-order vmcnt)
        if (k < NCHUNK - 1) asm volatile("s_waitcnt vmcnt(2)" ::: "memory");
        else                asm volatile("s_waitcnt vmcnt(0)" ::: "memory");

        const float* seg = &xbuf[k & 1][sg << 7];
        float acc = 0.0f, m0 = -1e30f, m1 = -1e30f, pw = alpha;
#pragma unroll
        for (int j = 0; j < SEG; ++j) {
            const float* rp = seg + ((j ^ s23) << 4);
            float4 c0 = *(const float4*)(rp + 0);
            float4 c1 = *(const float4*)(rp + 4);
            float4 c2 = *(const float4*)(rp + 8);
            float4 c3 = *(const float4*)(rp + 12);
            float y = dot16(wr, c0, c1, c2, c3);
            acc = fmaf(alpha, acc, y);
            m0  = fmaxf(m0, acc);
            m1  = fmaxf(m1, acc + pw);
            pw *= alpha;
        }
        const int gs = k * 64 + sg;
        sh_end[gs][co] = acc;
        // conservative round-UP quantization: mq = q/102 - 1 >= m (m<=1.5);
        // q==255 decodes to +huge (flags bad) -> never under-estimates.
        int q0 = (int)ceilf(fmaf(m0, 102.0f, 102.0f));
        int q1 = (int)ceilf(fmaf(m1, 102.0f, 102.0f));
        q0 = q0 < 0 ? 0 : (q0 > 255 ? 255 : q0);
        q1 = q1 < 0 ? 0 : (q1 > 255 ? 255 : q1);
        sh_q0[gs][co] = (uint8_t)q0;
        sh_q1[gs][co] = (uint8_t)q1;

        if (k < NCHUNK - 2) {
            // our ds_reads (and cert ds_writes) drained before refilling buf
            asm volatile("s_waitcnt lgkmcnt(0)" ::: "memory");
            const float* src = xb + (size_t)(k + 2) * 8192;
            float* bp = xbuf[k & 1];
            load_lds16(src + offA, bp + ldsA);
            load_lds16(src + offB, bp + ldsB);
        }
    }
    __syncthreads();   // all waves' cert entries visible

    // ---- composition + certification: 16 ch x 4 quarter-chains ------------
    if (tid < 64) {
        const int c  = tid & 15;
        const int qd = tid >> 4;
        const int s_begin = qd * 128;
        const int s_start = (qd == 0) ? 0 : s_begin - 20;   // warm-up
        float vs = 0.0f;
        uint32_t badw = 0;
        int bad = 0;
        for (int s = s_start; s < s_begin + 128; ++s) {
            if (s >= s_begin) {
                int q0 = sh_q0[s][c], q1 = sh_q1[s][c];
                float mm0 = (q0 == 255) ? 1e30f : fmaf((float)q0, 0.0098039216f, -1.0f);
                float mm1 = (q1 == 255) ? 1e30f : fmaf((float)q1, 0.0098039216f, -1.0f);
                float vsu = fminf(fmaxf(vs + 1e-3f, 0.0f), 1.0f);
                float bound = fmaf(1.0f - vsu, mm0, vsu * mm1);
                if (bound >= 0.999f) { badw |= 1u << (s & 31); bad = 1; }
                if ((s & 31) == 31) { sh_badseg[c][s >> 5] = badw; badw = 0; }
            }
            vs = fmaf(alpha8, vs, sh_end[s][c]);
        }
        if (bad) atomicOr(&sh_badch, 1 << c);
    }
    __syncthreads();

    // ---- parallel exact repair for cert-bad channels (rare) ---------------
    const int badmask = sh_badch;
    if (badmask) {
        // dense-zero s1t[b] so the scan2 phase never reads unwritten bytes
        uint4* sz = (uint4*)(s1t + (size_t)b * 16 * T_STEPS);
#pragma unroll
        for (int i = 0; i < 4; ++i) sz[i * 1024 + tid] = make_uint4(0u,0u,0u,0u);
        __syncthreads();   // zeroing ordered before repair spike writes

        int m = badmask;
        for (int i = 0; i < wv; ++i) m &= m - 1;
        if (ln == 0 && m) {
            const int c = __ffs(m) - 1;
            float wc[16];
#pragma unroll
            for (int i = 0; i < 16; ++i) wc[i] = one_m * w1[c * 16 + i];
            uint8_t* op = s1t + ((size_t)b * 16 + c) * T_STEPS;
            float v = 0.0f;
            int any = 0;
            for (int s = 0; s < NSEG; ++s) {
                if (!((sh_badseg[c][s >> 5] >> (s & 31)) & 1u)) {
                    // cert-good: no spike; linear jump via zero-state response
                    v = fmaf(alpha8, v, sh_end[s][c]);
                } else {
                    const float* xr0 = xb + (size_t)s * 128;
                    uint32_t sw0 = 0u, sw1 = 0u;
#pragma unroll
                    for (int j = 0; j < SEG; ++j) {
                        const float4* xr = (const float4*)(xr0 + j * 16);
                        float y  = dot16(wc, xr[0], xr[1], xr[2], xr[3]);
                        float sp = lif_step(v, y, alpha);
                        if (j < 4) sw0 |= ((uint32_t)(int)sp) << (j * 8);
                        else       sw1 |= ((uint32_t)(int)sp) << ((j - 4) * 8);
                    }
                    if (sw0 | sw1) {
                        *(uint2*)(op + s * 8) = make_uint2(sw0, sw1);
                        sh_bm1[s >> 1] = 1;
                        any = 1;
                    }
                }
            }
            if (any) sh_spike = 1;
        }
    }
    __syncthreads();   // orders repair writes + sh_spike/sh_bm1 for readers

    // ---- fused layer-2: sparse scan s1t -> s2t (+ sh_bm2) -----------------
    if (sh_spike) {
        if (tid < 32) {
            const int c2 = tid;
            float wr2[16];
#pragma unroll
            for (int i = 0; i < 16; ++i) wr2[i] = one_m * w2[c2 * 16 + i];
            const uint8_t* sb1 = s1t + (size_t)b * 16 * T_STEPS;
            uint4* op2 = (uint4*)(s2t + ((size_t)b * 32 + c2) * T_STEPS);
            const uint4* bmv = (const uint4*)sh_bm1;
            float v = 0.0f;
            for (int sb = 0; sb < 16; ++sb) {
                uint4 bm = bmv[sb];
                if ((bm.x | bm.y | bm.z | bm.w) == 0u) {
                    if (v != 0.0f) {
                        for (int blk = 0; blk < 16 && v != 0.0f; ++blk) {
#pragma unroll
                            for (int j = 0; j < 16; ++j) v *= alpha;
                        }
                    }
                    continue;
                }
                for (int blk = 0; blk < 16; ++blk) {
                    uint32_t d = (blk < 4) ? bm.x : (blk < 8) ? bm.y
                               : (blk < 12) ? bm.z : bm.w;
                    uint32_t byte = (d >> ((blk & 3) * 8)) & 0xffu;
                    if (byte == 0u) {
                        if (v != 0.0f) {
#pragma unroll
                            for (int j = 0; j < 16; ++j) v *= alpha;
                        }
                        continue;
                    }
                    const int tb = sb * 16 + blk;
                    const int t0 = tb * 16;
                    uint4 S[16];
#pragma unroll
                    for (int c = 0; c < 16; ++c)
                        S[c] = *(const uint4*)(sb1 + (size_t)c * T_STEPS + t0);
                    uint32_t w[4] = {0u, 0u, 0u, 0u};
#pragma unroll
                    for (int j = 0; j < 16; ++j) {
                        float xv[16];
#pragma unroll
                        for (int c = 0; c < 16; ++c) {
                            uint32_t dd = (j < 4) ? S[c].x : (j < 8) ? S[c].y
                                        : (j < 12) ? S[c].z : S[c].w;
                            xv[c] = ubf(dd, j & 3);
                        }
                        float p0 = fmaf(wr2[1], xv[1], wr2[0] * xv[0]);
                        p0 = fmaf(wr2[2], xv[2], p0);   p0 = fmaf(wr2[3], xv[3], p0);
                        float p1 = fmaf(wr2[5], xv[5], wr2[4] * xv[4]);
                        p1 = fmaf(wr2[6], xv[6], p1);   p1 = fmaf(wr2[7], xv[7], p1);
                        float p2 = fmaf(wr2[9], xv[9], wr2[8] * xv[8]);
                        p2 = fmaf(wr2[10], xv[10], p2); p2 = fmaf(wr2[11], xv[11], p2);
                        float p3 = fmaf(wr2[13], xv[13], wr2[12] * xv[12]);
                        p3 = fmaf(wr2[14], xv[14], p3); p3 = fmaf(wr2[15], xv[15], p3);
                        float xs = (p0 + p1) + (p2 + p3);
                        float s = lif_step(v, xs, alpha);
                        w[j >> 2] |= ((uint32_t)(int)s) << ((j & 3) * 8);
                    }
                    op2[tb] = make_uint4(w[0], w[1], w[2], w[3]);
                    if (w[0] | w[1] | w[2] | w[3]) { sh_bm2[tb] = 1; sh_flag2 = 1; }
                }
            }
        }
        __syncthreads();   // s2t/sh_bm2/sh_flag2 visible

        // ---- fused layer-3: sparse scan s2t -> out (pre-zeroed) -----------
        if (sh_flag2 && tid < 16) {
            const int c3 = tid;
            const bool active = (c3 < 10);
            float wr3[32];
#pragma unroll
            for (int i = 0; i < 32; ++i)
                wr3[i] = active ? (one_m * w3[c3 * 32 + i]) : 0.0f;
            const uint8_t* sb2 = s2t + (size_t)b * 32 * T_STEPS;
            const uint4* bmv2 = (const uint4*)sh_bm2;
            float* ob = out + (size_t)b * T_STEPS * 10 + c3;
            float v = 0.0f;
            for (int sb = 0; sb < 16; ++sb) {
                uint4 bm = bmv2[sb];
                if ((bm.x | bm.y | bm.z | bm.w) == 0u) {
                    if (v != 0.0f) {
                        for (int blk = 0; blk < 16 && v != 0.0f; ++blk) {
#pragma unroll
                            for (int j = 0; j < 16; ++j) v *= alpha;
                        }
                    }
                    continue;
                }
                for (int blk = 0; blk < 16; ++blk) {
                    uint32_t d = (blk < 4) ? bm.x : (blk < 8) ? bm.y
                               : (blk < 12) ? bm.z : bm.w;
                    uint32_t byte = (d >> ((blk & 3) * 8)) & 0xffu;
                    if (byte == 0u) {
                        if (v != 0.0f) {
#pragma unroll
                            for (int j = 0; j < 16; ++j) v *= alpha;
                        }
                        continue;
                    }
                    const int t0 = (sb * 16 + blk) * 16;
                    uint4 S[32];
#pragma unroll
                    for (int c = 0; c < 32; ++c)
                        S[c] = *(const uint4*)(sb2 + (size_t)c * T_STEPS + t0);
#pragma unroll
                    for (int j = 0; j < 16; ++j) {
                        float xv[32];
#pragma unroll
                        for (int c = 0; c < 32; ++c) {
                            uint32_t dd = (j < 4) ? S[c].x : (j < 8) ? S[c].y
                                        : (j < 12) ? S[c].z : S[c].w;
                            xv[c] = ubf(dd, j & 3);
                        }
                        float p0 = fmaf(wr3[1], xv[1], wr3[0] * xv[0]);
                        p0 = fmaf(wr3[2],  xv[2],  p0); p0 = fmaf(wr3[3],  xv[3],  p0);
                        p0 = fmaf(wr3[4],  xv[4],  p0); p0 = fmaf(wr3[5],  xv[5],  p0);
                        p0 = fmaf(wr3[6],  xv[6],  p0); p0 = fmaf(wr3[7],  xv[7],  p0);
                        float p1 = fmaf(wr3[9], xv[9], wr3[8] * xv[8]);
                        p1 = fmaf(wr3[10], xv[10], p1); p1 = fmaf(wr3[11], xv[11], p1);
                        p1 = fmaf(wr3[12], xv[12], p1); p1 = fmaf(wr3[13], xv[13], p1);
                        p1 = fmaf(wr3[14], xv[14], p1); p1 = fmaf(wr3[15], xv[15], p1);
                        float p2 = fmaf(wr3[17], xv[17], wr3[16] * xv[16]);
                        p2 = fmaf(wr3[18], xv[18], p2); p2 = fmaf(wr3[19], xv[19], p2);
                        p2 = fmaf(wr3[20], xv[20], p2); p2 = fmaf(wr3[21], xv[21], p2);
                        p2 = fmaf(wr3[22], xv[22], p2); p2 = fmaf(wr3[23], xv[23], p2);
                        float p3 = fmaf(wr3[25], xv[25], wr3[24] * xv[24]);
                        p3 = fmaf(wr3[26], xv[26], p3); p3 = fmaf(wr3[27], xv[27], p3);
                        p3 = fmaf(wr3[28], xv[28], p3); p3 = fmaf(wr3[29], xv[29], p3);
                        p3 = fmaf(wr3[30], xv[30], p3); p3 = fmaf(wr3[31], xv[31], p3);
                        float xs = (p0 + p1) + (p2 + p3);
                        float s = lif_step(v, xs, alpha);
                        if (active && s != 0.0f) ob[(size_t)(t0 + j) * 10] = s;
                    }
                }
            }
        }
    }
}

extern "C" void kernel_launch(void* const* d_in, const int* in_sizes, int n_in,
                              void* d_out, int out_size, void* d_ws, size_t ws_size,
                              hipStream_t stream)
{
    const float* data = (const float*)d_in[0];
    const float* w1   = (const float*)d_in[1];
    const float* w2   = (const float*)d_in[2];
    const float* w3   = (const float*)d_in[3];
    float* out = (float*)d_out;

    // ws layout (48 MiB):
    //   [0, 16M)    s1t  u8 [256][16][4096]  (dense-zeroed only for bad b)
    //   [16M, 48M)  s2t  u8 [256][32][4096]  (sparse: only bm2-set blocks valid)
    uint8_t* ws  = (uint8_t*)d_ws;
    uint8_t* s1t = ws;
    uint8_t* s2t = ws + (16u << 20);

    const float alpha  = expf(-1.0f / 20.0f);
    const float one_m  = 1.0f - alpha;
    const float alpha8 = expf(-8.0f / 20.0f);

    fused<<<BATCH, 1024, 0, stream>>>(data, w1, w2, w3, out, s1t, s2t,
                                      alpha, one_m, alpha8);
}

// Round 3
// 165.168 us; speedup vs baseline: 1.3059x; 1.3059x over previous
//
#include <hip/hip_runtime.h>
#include <stdint.h>
#include <math.h>

#define T_STEPS 4096
#define BATCH   256
#define NB_BLK  256      // 16-step cert segments == spike blocks per chain

// LIF step, threshold=1:  v'=alpha*v+xs; s=max(floor(v'),0); v=v'-s
// Identity: v_new = min(v', fract(v')); s = v' - v_new (exact fp32).
// No-spike step (0<=v'<1 or v'<0) is EXACTLY v = fma(alpha, v, xs).
__device__ __forceinline__ float lif_step(float& v, float xs, float alpha) {
    float vp = fmaf(alpha, v, xs);
    float fr = vp - floorf(vp);
    float vn = fminf(vp, fr);
    float s  = vp - vn;
    v = vn;
    return s;
}

__device__ __forceinline__ float ubf(uint32_t w, int k) {
    return (float)((w >> (k * 8)) & 0xffu);
}

__device__ __forceinline__ float dot16(const float wr[16],
    float4 c0, float4 c1, float4 c2, float4 c3)
{
    float p0 = fmaf(wr[1], c0.y, wr[0] * c0.x);
    p0 = fmaf(wr[2], c0.z, p0);  p0 = fmaf(wr[3], c0.w, p0);
    float p1 = fmaf(wr[5], c1.y, wr[4] * c1.x);
    p1 = fmaf(wr[6], c1.z, p1);  p1 = fmaf(wr[7], c1.w, p1);
    float p2 = fmaf(wr[9], c2.y, wr[8] * c2.x);
    p2 = fmaf(wr[10], c2.z, p2); p2 = fmaf(wr[11], c2.w, p2);
    float p3 = fmaf(wr[13], c3.y, wr[12] * c3.x);
    p3 = fmaf(wr[14], c3.z, p3); p3 = fmaf(wr[15], c3.w, p3);
    return (p0 + p1) + (p2 + p3);
}

// R16: REGISTER-STAGED double buffer (global->VGPR->ds_write), replacing
// global_load_lds.  Evidence: R14 (64KB chunks) and R15 (32KB chunks) both
// showed ~40K-cycle per-iteration time INDEPENDENT of chunk bytes and of
// compute -> the LDS-DMA path itself serializes (~600-1300 cy per 1KB
// global_load_lds instr per CU).  Normal global_load_dwordx4 pipelines at
// TB/s; so: issue chunk k+1's 4 loads per thread BEFORE computing chunk k
// from LDS, ds_write them after (compiler inserts the vmcnt wait before the
// ds_write; DS ops are wave-ordered so write->read needs no explicit wait).
// Regions stay wave-private (wave wv owns segments wv*4..wv*4+3; its compute
// lanes sg=tid>>4 read exactly those) -> still ZERO in-loop barriers.
// Layout: segment s at float offset s*260 (1040B pitch, 16B-aligned since
// 260%4==0); the 4 in-wave segments differ by 4 banks -> conflict-free
// ds_read_b128 with 16-lane broadcast, and ds_write_b128 is volume-limited
// only.  Certs fp32 (R14 scheme).  Tails (scan2/scan3) stay FUSED (R15 win:
// total-minus-kernel 107us -> 76us): bitmaps/flags in LDS, 1 launch total.
__global__ __launch_bounds__(1024) void fused(
    const float* __restrict__ x, const float* __restrict__ w1,
    const float* __restrict__ w2, const float* __restrict__ w3,
    float* __restrict__ out, uint8_t* __restrict__ s1t,
    uint8_t* __restrict__ s2t,
    float alpha, float one_m, float alpha16)
{
    const int tid = threadIdx.x;
    const int b   = blockIdx.x;

    __shared__ __align__(16) float xbuf[16640];          // 65 KiB chunk buf
    __shared__ float   sh_end[NB_BLK][16];               // 16 KiB
    __shared__ float   sh_m0[NB_BLK][16];                // 16 KiB
    __shared__ float   sh_m1[NB_BLK][16];                // 16 KiB
    __shared__ uint8_t sh_badseg[16][NB_BLK];            // 4 KiB
    __shared__ uint8_t sh_bm1[NB_BLK];                   // 256 B
    __shared__ uint8_t sh_bm2[NB_BLK];                   // 256 B
    __shared__ int     sh_badch, sh_spike, sh_flag2;

    const int co = tid & 15;
    const int sg = tid >> 4;          // 0..63 in-chunk segment
    const int wv = tid >> 6;          // wave 0..15
    const int ln = tid & 63;          // lane 0..63

    const float* xb = x + (size_t)b * T_STEPS * 16;      // 65536 floats
    const float4* xq4 = (const float4*)xb;               // 16384 float4

    // ---- stage chunk 0 into regs (issued first; lands under init below) ---
    float4 stg[4];
#pragma unroll
    for (int q = 0; q < 4; ++q)
        stg[q] = xq4[(wv * 4 + q) * 64 + ln];

    // ---- LDS flag/bitmap init ---------------------------------------------
    if (tid < 64)        ((uint32_t*)sh_bm1)[tid] = 0u;
    else if (tid < 128)  ((uint32_t*)sh_bm2)[tid - 64] = 0u;
    else if (tid == 128) { sh_badch = 0; sh_spike = 0; sh_flag2 = 0; }

    // ---- zero out[b] (overlaps chunk-0 load latency) ----------------------
    float4* o4 = (float4*)(out + (size_t)b * T_STEPS * 10);   // 10240 float4
    float4 z4 = make_float4(0.f, 0.f, 0.f, 0.f);
#pragma unroll
    for (int i = 0; i < 10; ++i) o4[i * 1024 + tid] = z4;

    float wr[16];
#pragma unroll
    for (int i = 0; i < 16; ++i) wr[i] = one_m * w1[co * 16 + i];

    const int sbase = sg * 260;                 // compute read base (floats)
    const int wbase = (wv * 4) * 260 + ln * 4;  // staging write base (floats)

    // ---- ds_write chunk 0 (compiler waits the loads here) -----------------
#pragma unroll
    for (int q = 0; q < 4; ++q)
        *(float4*)&xbuf[wbase + q * 260] = stg[q];

#pragma unroll
    for (int k = 0; k < 4; ++k) {
        // issue next-chunk loads FIRST -> they fly under this chunk's compute
        if (k < 3) {
#pragma unroll
            for (int q = 0; q < 4; ++q)
                stg[q] = xq4[((k + 1) * 64 + wv * 4 + q) * 64 + ln];
        }

        // compute chunk k from LDS (wave-private region, DS ops wave-ordered)
        float acc = 0.0f, m0 = -1e30f, m1 = -1e30f, pw = alpha;
#pragma unroll
        for (int j = 0; j < 16; ++j) {
            const float* rp = &xbuf[sbase + j * 16];
            float4 c0 = *(const float4*)(rp + 0);
            float4 c1 = *(const float4*)(rp + 4);
            float4 c2 = *(const float4*)(rp + 8);
            float4 c3 = *(const float4*)(rp + 12);
            float y = dot16(wr, c0, c1, c2, c3);
            acc = fmaf(alpha, acc, y);
            m0  = fmaxf(m0, acc);
            m1  = fmaxf(m1, acc + pw);
            pw *= alpha;
        }
        const int gs = k * 64 + sg;
        sh_end[gs][co] = acc;
        sh_m0[gs][co]  = m0;
        sh_m1[gs][co]  = m1;

        // overwrite our region with chunk k+1 (program order after our reads)
        if (k < 3) {
#pragma unroll
            for (int q = 0; q < 4; ++q)
                *(float4*)&xbuf[wbase + q * 260] = stg[q];
        }
    }
    __syncthreads();   // all waves' cert entries visible

    // ---- serial composition + per-channel/per-segment certification -------
    if (tid < 16) {
        const int c = tid;
        float vs = 0.0f;
        int bad = 0;
#pragma unroll 8
        for (int s = 0; s < NB_BLK; ++s) {
            float vsu = fminf(fmaxf(vs + 1e-3f, 0.0f), 1.0f);
            float bound = fmaf(1.0f - vsu, sh_m0[s][c], vsu * sh_m1[s][c]);
            int sb = (bound >= 0.999f) ? 1 : 0;
            sh_badseg[c][s] = (uint8_t)sb;
            bad |= sb;
            vs = fmaf(alpha16, vs, sh_end[s][c]);
        }
        if (bad) atomicOr(&sh_badch, 1 << c);
    }
    __syncthreads();

    // ---- parallel exact repair for cert-bad channels (rare) ---------------
    const int badmask = sh_badch;
    if (badmask) {
        // dense-zero s1t[b] so the scan2 phase never reads unwritten bytes
        uint4* sz = (uint4*)(s1t + (size_t)b * 16 * T_STEPS);
#pragma unroll
        for (int i = 0; i < 4; ++i) sz[i * 1024 + tid] = make_uint4(0u,0u,0u,0u);
        __syncthreads();   // zeroing ordered before repair spike writes

        // wave wv repairs the wv-th set bit (one lane per wave; disjoint rows)
        int m = badmask;
        for (int i = 0; i < wv; ++i) m &= m - 1;
        if (ln == 0 && m) {
            const int c = __ffs(m) - 1;
            float wc[16];
#pragma unroll
            for (int i = 0; i < 16; ++i) wc[i] = one_m * w1[c * 16 + i];
            uint8_t* op = s1t + ((size_t)b * 16 + c) * T_STEPS;
            float v = 0.0f;
            int any = 0;
            for (int s = 0; s < NB_BLK; ++s) {
                if (!sh_badseg[c][s]) {
                    // cert-good: no spike; linear jump via zero-state response
                    v = fmaf(alpha16, v, sh_end[s][c]);
                } else {
                    const float4* xr = (const float4*)xb + (size_t)s * 64;
                    uint32_t w[4] = {0u,0u,0u,0u};
#pragma unroll 4
                    for (int j = 0; j < 16; ++j) {
                        float y  = dot16(wc, xr[j*4+0], xr[j*4+1],
                                              xr[j*4+2], xr[j*4+3]);
                        float sp = lif_step(v, y, alpha);
                        w[j >> 2] |= ((uint32_t)(int)sp) << ((j & 3) * 8);
                    }
                    if (w[0] | w[1] | w[2] | w[3]) {
                        *(uint4*)(op + s * 16) = make_uint4(w[0], w[1], w[2], w[3]);
                        sh_bm1[s] = 1;
                        any = 1;
                    }
                }
            }
            if (any) sh_spike = 1;
        }
    }
    __syncthreads();   // orders repair writes + sh_spike/sh_bm1 for readers

    // ---- fused layer-2: sparse scan s1t -> s2t (+ sh_bm2) -----------------
    if (sh_spike) {
        if (tid < 32) {
            const int c2 = tid;
            float wr2[16];
#pragma unroll
            for (int i = 0; i < 16; ++i) wr2[i] = one_m * w2[c2 * 16 + i];
            const uint8_t* sb1 = s1t + (size_t)b * 16 * T_STEPS;
            uint4* op2 = (uint4*)(s2t + ((size_t)b * 32 + c2) * T_STEPS);
            const uint4* bmv = (const uint4*)sh_bm1;
            uint8_t* bm2p = sh_bm2;
            float v = 0.0f;
            for (int sb = 0; sb < 16; ++sb) {
                uint4 bm = bmv[sb];
                if ((bm.x | bm.y | bm.z | bm.w) == 0u) {
                    if (v != 0.0f) {
                        for (int blk = 0; blk < 16 && v != 0.0f; ++blk) {
#pragma unroll
                            for (int j = 0; j < 16; ++j) v *= alpha;
                        }
                    }
                    continue;
                }
                for (int blk = 0; blk < 16; ++blk) {
                    uint32_t d = (blk < 4) ? bm.x : (blk < 8) ? bm.y
                               : (blk < 12) ? bm.z : bm.w;
                    uint32_t byte = (d >> ((blk & 3) * 8)) & 0xffu;
                    if (byte == 0u) {
                        if (v != 0.0f) {
#pragma unroll
                            for (int j = 0; j < 16; ++j) v *= alpha;
                        }
                        continue;
                    }
                    const int tb = sb * 16 + blk;
                    const int t0 = tb * 16;
                    uint4 S[16];
#pragma unroll
                    for (int c = 0; c < 16; ++c)
                        S[c] = *(const uint4*)(sb1 + (size_t)c * T_STEPS + t0);
                    uint32_t w[4] = {0u, 0u, 0u, 0u};
#pragma unroll
                    for (int j = 0; j < 16; ++j) {
                        float xv[16];
#pragma unroll
                        for (int c = 0; c < 16; ++c) {
                            uint32_t dd = (j < 4) ? S[c].x : (j < 8) ? S[c].y
                                        : (j < 12) ? S[c].z : S[c].w;
                            xv[c] = ubf(dd, j & 3);
                        }
                        float p0 = fmaf(wr2[1], xv[1], wr2[0] * xv[0]);
                        p0 = fmaf(wr2[2], xv[2], p0);   p0 = fmaf(wr2[3], xv[3], p0);
                        float p1 = fmaf(wr2[5], xv[5], wr2[4] * xv[4]);
                        p1 = fmaf(wr2[6], xv[6], p1);   p1 = fmaf(wr2[7], xv[7], p1);
                        float p2 = fmaf(wr2[9], xv[9], wr2[8] * xv[8]);
                        p2 = fmaf(wr2[10], xv[10], p2); p2 = fmaf(wr2[11], xv[11], p2);
                        float p3 = fmaf(wr2[13], xv[13], wr2[12] * xv[12]);
                        p3 = fmaf(wr2[14], xv[14], p3); p3 = fmaf(wr2[15], xv[15], p3);
                        float xs = (p0 + p1) + (p2 + p3);
                        float s = lif_step(v, xs, alpha);
                        w[j >> 2] |= ((uint32_t)(int)s) << ((j & 3) * 8);
                    }
                    op2[tb] = make_uint4(w[0], w[1], w[2], w[3]);
                    if (w[0] | w[1] | w[2] | w[3]) { bm2p[tb] = 1; sh_flag2 = 1; }
                }
            }
        }
        __syncthreads();   // s2t/sh_bm2/sh_flag2 visible

        // ---- fused layer-3: sparse scan s2t -> out (pre-zeroed) -----------
        if (sh_flag2 && tid < 16) {
            const int c3 = tid;
            const bool active = (c3 < 10);
            float wr3[32];
#pragma unroll
            for (int i = 0; i < 32; ++i)
                wr3[i] = active ? (one_m * w3[c3 * 32 + i]) : 0.0f;
            const uint8_t* sb2 = s2t + (size_t)b * 32 * T_STEPS;
            const uint4* bmv2 = (const uint4*)sh_bm2;
            float* ob = out + (size_t)b * T_STEPS * 10 + c3;
            float v = 0.0f;
            for (int sb = 0; sb < 16; ++sb) {
                uint4 bm = bmv2[sb];
                if ((bm.x | bm.y | bm.z | bm.w) == 0u) {
                    if (v != 0.0f) {
                        for (int blk = 0; blk < 16 && v != 0.0f; ++blk) {
#pragma unroll
                            for (int j = 0; j < 16; ++j) v *= alpha;
                        }
                    }
                    continue;
                }
                for (int blk = 0; blk < 16; ++blk) {
                    uint32_t d = (blk < 4) ? bm.x : (blk < 8) ? bm.y
                               : (blk < 12) ? bm.z : bm.w;
                    uint32_t byte = (d >> ((blk & 3) * 8)) & 0xffu;
                    if (byte == 0u) {
                        if (v != 0.0f) {
#pragma unroll
                            for (int j = 0; j < 16; ++j) v *= alpha;
                        }
                        continue;
                    }
                    const int t0 = (sb * 16 + blk) * 16;
                    uint4 S[32];
#pragma unroll
                    for (int c = 0; c < 32; ++c)
                        S[c] = *(const uint4*)(sb2 + (size_t)c * T_STEPS + t0);
#pragma unroll
                    for (int j = 0; j < 16; ++j) {
                        float xv[32];
#pragma unroll
                        for (int c = 0; c < 32; ++c) {
                            uint32_t dd = (j < 4) ? S[c].x : (j < 8) ? S[c].y
                                        : (j < 12) ? S[c].z : S[c].w;
                            xv[c] = ubf(dd, j & 3);
                        }
                        float p0 = fmaf(wr3[1], xv[1], wr3[0] * xv[0]);
                        p0 = fmaf(wr3[2],  xv[2],  p0); p0 = fmaf(wr3[3],  xv[3],  p0);
                        p0 = fmaf(wr3[4],  xv[4],  p0); p0 = fmaf(wr3[5],  xv[5],  p0);
                        p0 = fmaf(wr3[6],  xv[6],  p0); p0 = fmaf(wr3[7],  xv[7],  p0);
                        float p1 = fmaf(wr3[9], xv[9], wr3[8] * xv[8]);
                        p1 = fmaf(wr3[10], xv[10], p1); p1 = fmaf(wr3[11], xv[11], p1);
                        p1 = fmaf(wr3[12], xv[12], p1); p1 = fmaf(wr3[13], xv[13], p1);
                        p1 = fmaf(wr3[14], xv[14], p1); p1 = fmaf(wr3[15], xv[15], p1);
                        float p2 = fmaf(wr3[17], xv[17], wr3[16] * xv[16]);
                        p2 = fmaf(wr3[18], xv[18], p2); p2 = fmaf(wr3[19], xv[19], p2);
                        p2 = fmaf(wr3[20], xv[20], p2); p2 = fmaf(wr3[21], xv[21], p2);
                        p2 = fmaf(wr3[22], xv[22], p2); p2 = fmaf(wr3[23], xv[23], p2);
                        float p3 = fmaf(wr3[25], xv[25], wr3[24] * xv[24]);
                        p3 = fmaf(wr3[26], xv[26], p3); p3 = fmaf(wr3[27], xv[27], p3);
                        p3 = fmaf(wr3[28], xv[28], p3); p3 = fmaf(wr3[29], xv[29], p3);
                        p3 = fmaf(wr3[30], xv[30], p3); p3 = fmaf(wr3[31], xv[31], p3);
                        float xs = (p0 + p1) + (p2 + p3);
                        float s = lif_step(v, xs, alpha);
                        if (active && s != 0.0f) ob[(size_t)(t0 + j) * 10] = s;
                    }
                }
            }
        }
    }
}

extern "C" void kernel_launch(void* const* d_in, const int* in_sizes, int n_in,
                              void* d_out, int out_size, void* d_ws, size_t ws_size,
                              hipStream_t stream)
{
    const float* data = (const float*)d_in[0];
    const float* w1   = (const float*)d_in[1];
    const float* w2   = (const float*)d_in[2];
    const float* w3   = (const float*)d_in[3];
    float* out = (float*)d_out;

    // ws layout (48 MiB):
    //   [0, 16M)    s1t  u8 [256][16][4096]  (dense-zeroed only for bad b)
    //   [16M, 48M)  s2t  u8 [256][32][4096]  (sparse: only bm2-set blocks valid)
    uint8_t* ws  = (uint8_t*)d_ws;
    uint8_t* s1t = ws;
    uint8_t* s2t = ws + (16u << 20);

    const float alpha   = expf(-1.0f / 20.0f);
    const float one_m   = 1.0f - alpha;
    const float alpha16 = expf(-16.0f / 20.0f);

    fused<<<BATCH, 1024, 0, stream>>>(data, w1, w2, w3, out, s1t, s2t,
                                      alpha, one_m, alpha16);
}